// Round 2
// baseline (36.248 us; speedup 1.0000x reference)
//
#include <hip/hip_runtime.h>
#include <float.h>

#define B_TOK 256
#define N_OUT 512
#define K_IN  1024

// ---------------- Kernel A: transpose w[512][1024] -> wT[1024][512] ----------------
// grid (K/64, N/64) = (16,8), block 256 (64 lanes x 4 rows). LDS 64x65 pad: conflict-free.
__global__ __launch_bounds__(256)
void w_transpose(const float* __restrict__ w, float* __restrict__ wT) {
    __shared__ float t[64][65];
    const int k0 = blockIdx.x * 64;
    const int n0 = blockIdx.y * 64;
    const int tx = threadIdx.x & 63;   // along k on load, along n on store
    const int ty = threadIdx.x >> 6;   // 0..3
#pragma unroll
    for (int j = 0; j < 64; j += 4) {
        // coalesced read along k (lane = k)
        t[tx][ty + j] = w[(size_t)(n0 + ty + j) * K_IN + (k0 + tx)];
    }
    __syncthreads();
#pragma unroll
    for (int j = 0; j < 64; j += 4) {
        // coalesced write along n (lane = n); LDS read t[c][tx] conflict-free
        wT[(size_t)(k0 + ty + j) * N_OUT + (n0 + tx)] = t[ty + j][tx];
    }
}

// ---------------- Kernel B: fused MAM ----------------
// grid (B/8, N/64) = (32,8) = 256 blocks, block 512 = 8 waves.
// wave = one k-chunk of 128; lane = one n (coalesced wT dword loads, 64x4B=256B);
// x loads are wave-uniform -> scalarized by compiler (s_load).
// Per-thread micro-tile: 8 b-rows reuse each w value 8x.
__global__ __launch_bounds__(512)
void mam_fused(const float* __restrict__ x, const float* __restrict__ wT,
               const float* __restrict__ bias, float* __restrict__ out) {
    const int bg = blockIdx.x;             // b-group: b0 = bg*8
    const int ng = blockIdx.y;             // n-group: n0 = ng*64
    const int wv = threadIdx.x >> 6;       // wave id 0..7 -> k-chunk
    const int ln = threadIdx.x & 63;       // lane -> n offset
    const int b0 = bg * 8;
    const int n  = ng * 64 + ln;
    const int kc = wv * 128;

    const float* wp = wT + (size_t)kc * N_OUT + n;      // stride N_OUT per k
    const float* xp = x + (size_t)b0 * K_IN + kc;       // wave-uniform

    float mx[8], mn[8];
#pragma unroll
    for (int r = 0; r < 8; ++r) { mx[r] = -FLT_MAX; mn[r] = FLT_MAX; }

#pragma unroll 8
    for (int k = 0; k < 128; k += 2) {
        const float w0 = wp[(size_t)(k + 0) * N_OUT];
        const float w1 = wp[(size_t)(k + 1) * N_OUT];
#pragma unroll
        for (int r = 0; r < 8; ++r) {
            const float p0 = xp[(size_t)r * K_IN + k + 0] * w0;
            const float p1 = xp[(size_t)r * K_IN + k + 1] * w1;
            mx[r] = fmaxf(fmaxf(mx[r], p0), p1);   // -> v_max3_f32
            mn[r] = fminf(fminf(mn[r], p0), p1);   // -> v_min3_f32
        }
    }

    // combine 8 wave-partials via LDS: [mx/mn][wave][n][b] = 32 KB
    __shared__ float red[2][8][64][8];
#pragma unroll
    for (int r = 0; r < 8; ++r) {
        red[0][wv][ln][r] = mx[r];
        red[1][wv][ln][r] = mn[r];
    }
    __syncthreads();

    // 512 threads -> 512 outputs of this block: b = tid&7, nn = tid>>3
    const int b  = threadIdx.x & 7;
    const int nn = threadIdx.x >> 3;
    float MX = -FLT_MAX, MN = FLT_MAX;
#pragma unroll
    for (int v = 0; v < 8; ++v) {
        MX = fmaxf(MX, red[0][v][nn][b]);   // lane-consecutive addr: conflict-free
        MN = fminf(MN, red[1][v][nn][b]);
    }
    out[(size_t)(b0 + b) * N_OUT + ng * 64 + nn] = MX + MN + bias[ng * 64 + nn];
}

// ---------------- Fallback (workspace too small) ----------------
__global__ __launch_bounds__(256)
void mam_simple(const float* __restrict__ x, const float* __restrict__ w,
                const float* __restrict__ bias, float* __restrict__ out) {
    const int idx = blockIdx.x * 256 + threadIdx.x;
    const int b = idx / N_OUT, n = idx % N_OUT;
    const float* xr = x + (size_t)b * K_IN;
    const float* wr = w + (size_t)n * K_IN;
    float mx = -FLT_MAX, mn = FLT_MAX;
#pragma unroll 4
    for (int k = 0; k < K_IN; k += 4) {
        const float4 xv = *reinterpret_cast<const float4*>(xr + k);
        const float4 wv = *reinterpret_cast<const float4*>(wr + k);
        const float p0 = xv.x * wv.x, p1 = xv.y * wv.y;
        const float p2 = xv.z * wv.z, p3 = xv.w * wv.w;
        mx = fmaxf(fmaxf(mx, p0), p1);
        mx = fmaxf(fmaxf(mx, p2), p3);
        mn = fminf(fminf(mn, p0), p1);
        mn = fminf(fminf(mn, p2), p3);
    }
    out[idx] = mx + mn + bias[n];
}

extern "C" void kernel_launch(void* const* d_in, const int* in_sizes, int n_in,
                              void* d_out, int out_size, void* d_ws, size_t ws_size,
                              hipStream_t stream) {
    const float* x    = (const float*)d_in[0];   // [256,1024]
    const float* w    = (const float*)d_in[1];   // [512,1024]
    const float* bias = (const float*)d_in[2];   // [512]
    float* out = (float*)d_out;                  // [256,512] f32

    const size_t need = (size_t)K_IN * N_OUT * sizeof(float);   // 2 MB for wT

    if (ws_size >= need) {
        float* wT = (float*)d_ws;
        w_transpose<<<dim3(K_IN / 64, N_OUT / 64), 256, 0, stream>>>(w, wT);
        mam_fused<<<dim3(B_TOK / 8, N_OUT / 64), 512, 0, stream>>>(x, wT, bias, out);
    } else {
        mam_simple<<<(B_TOK * N_OUT) / 256, 256, 0, stream>>>(x, w, bias, out);
    }
}

// Round 3
// 31.545 us; speedup vs baseline: 1.1491x; 1.1491x over previous
//
#include <hip/hip_runtime.h>
#include <float.h>

#define B_TOK 256
#define N_OUT 512
#define K_IN  1024

#define KC_NUM 16                 // k-chunks = partial planes
#define KC_LEN (K_IN / KC_NUM)    // 64 k per chunk
#define KSUB   (KC_LEN / 2)       // 32 k per wave (2 k-subs per block)

// ---------------- Kernel A: transpose w[512][1024] -> wT[1024][512] ----------------
__global__ __launch_bounds__(256)
void w_transpose(const float* __restrict__ w, float* __restrict__ wT) {
    __shared__ float t[64][65];
    const int k0 = blockIdx.x * 64;
    const int n0 = blockIdx.y * 64;
    const int tx = threadIdx.x & 63;
    const int ty = threadIdx.x >> 6;
#pragma unroll
    for (int j = 0; j < 64; j += 4)
        t[tx][ty + j] = w[(size_t)(n0 + ty + j) * K_IN + (k0 + tx)];
    __syncthreads();
#pragma unroll
    for (int j = 0; j < 64; j += 4)
        wT[(size_t)(k0 + ty + j) * N_OUT + (n0 + tx)] = t[ty + j][tx];
}

// ---------------- Stage 1: partial max/min over one 64-k chunk ----------------
// grid (32 b-groups, 16 k-chunks) = 512 blocks; block 256 = 4 waves.
// wave (readfirstlane'd): nh = w&1 -> n half; ks = w>>1 -> 32-k sub-chunk.
// thread: 4 consecutive n (float4 from wT, coalesced 1KB/wave) x 8 b rows.
// x addresses are provably wave-uniform -> scalar s_load pipe.
__global__ __launch_bounds__(256)
void mam_stage1(const float* __restrict__ x, const float* __restrict__ wT,
                float* __restrict__ pmx, float* __restrict__ pmn) {
    const int bg  = blockIdx.x;
    const int kc  = blockIdx.y;
    const int tid = threadIdx.x;
    const int wv  = __builtin_amdgcn_readfirstlane(tid >> 6);  // 0..3, uniform
    const int ln  = tid & 63;
    const int nh  = wv & 1;
    const int ks  = wv >> 1;
    const int b0  = bg * 8;
    const int k0  = kc * KC_LEN + ks * KSUB;
    const int nloc = nh * 256 + ln * 4;

    const float* wp = wT + (size_t)k0 * N_OUT + nloc;
    const float* xr = x + (size_t)b0 * K_IN + k0;   // uniform base

    float4 mx[8], mn[8];
#pragma unroll
    for (int b = 0; b < 8; ++b) {
        mx[b] = make_float4(-FLT_MAX, -FLT_MAX, -FLT_MAX, -FLT_MAX);
        mn[b] = make_float4( FLT_MAX,  FLT_MAX,  FLT_MAX,  FLT_MAX);
    }

#pragma unroll 4
    for (int kk = 0; kk < KSUB; kk += 2) {
        const float4 w0 = *reinterpret_cast<const float4*>(wp + (size_t)(kk + 0) * N_OUT);
        const float4 w1 = *reinterpret_cast<const float4*>(wp + (size_t)(kk + 1) * N_OUT);
#pragma unroll
        for (int b = 0; b < 8; ++b) {
            const float2 xv = *reinterpret_cast<const float2*>(xr + (size_t)b * K_IN + kk);
            const float p0x = xv.x * w0.x, p1x = xv.y * w1.x;
            const float p0y = xv.x * w0.y, p1y = xv.y * w1.y;
            const float p0z = xv.x * w0.z, p1z = xv.y * w1.z;
            const float p0w = xv.x * w0.w, p1w = xv.y * w1.w;
            mx[b].x = fmaxf(fmaxf(mx[b].x, p0x), p1x);  // -> v_max3_f32
            mn[b].x = fminf(fminf(mn[b].x, p0x), p1x);  // -> v_min3_f32
            mx[b].y = fmaxf(fmaxf(mx[b].y, p0y), p1y);
            mn[b].y = fminf(fminf(mn[b].y, p0y), p1y);
            mx[b].z = fmaxf(fmaxf(mx[b].z, p0z), p1z);
            mn[b].z = fminf(fminf(mn[b].z, p0z), p1z);
            mx[b].w = fmaxf(fmaxf(mx[b].w, p0w), p1w);
            mn[b].w = fminf(fminf(mn[b].w, p0w), p1w);
        }
    }

    // combine the 2 k-subs via LDS (64KB), then write one partial plane pair
    __shared__ float rmx[2][8][N_OUT];
    __shared__ float rmn[2][8][N_OUT];
#pragma unroll
    for (int b = 0; b < 8; ++b) {
        *reinterpret_cast<float4*>(&rmx[ks][b][nloc]) = mx[b];  // contiguous 1KB/wave
        *reinterpret_cast<float4*>(&rmn[ks][b][nloc]) = mn[b];
    }
    __syncthreads();

    const int nl = tid * 2;   // 256 threads x 2 n = 512
#pragma unroll
    for (int b = 0; b < 8; ++b) {
        const float2 a0 = *reinterpret_cast<const float2*>(&rmx[0][b][nl]);
        const float2 a1 = *reinterpret_cast<const float2*>(&rmx[1][b][nl]);
        const float2 i0 = *reinterpret_cast<const float2*>(&rmn[0][b][nl]);
        const float2 i1 = *reinterpret_cast<const float2*>(&rmn[1][b][nl]);
        float2 MX, MN;
        MX.x = fmaxf(a0.x, a1.x); MX.y = fmaxf(a0.y, a1.y);
        MN.x = fminf(i0.x, i1.x); MN.y = fminf(i0.y, i1.y);
        const size_t o = ((size_t)kc * B_TOK + (b0 + b)) * N_OUT + nl;
        *reinterpret_cast<float2*>(&pmx[o]) = MX;
        *reinterpret_cast<float2*>(&pmn[o]) = MN;
    }
}

// ---------------- Stage 2: combine 16 planes + bias ----------------
__global__ __launch_bounds__(256)
void mam_stage2(const float* __restrict__ pmx, const float* __restrict__ pmn,
                const float* __restrict__ bias, float* __restrict__ out) {
    const size_t i4 = ((size_t)blockIdx.x * 256 + threadIdx.x) * 4;  // 0..131068
    const size_t plane = (size_t)B_TOK * N_OUT;
    float4 MX = *reinterpret_cast<const float4*>(pmx + i4);
    float4 MN = *reinterpret_cast<const float4*>(pmn + i4);
#pragma unroll
    for (int p = 1; p < KC_NUM; ++p) {
        const float4 a = *reinterpret_cast<const float4*>(pmx + (size_t)p * plane + i4);
        const float4 i = *reinterpret_cast<const float4*>(pmn + (size_t)p * plane + i4);
        MX.x = fmaxf(MX.x, a.x); MX.y = fmaxf(MX.y, a.y);
        MX.z = fmaxf(MX.z, a.z); MX.w = fmaxf(MX.w, a.w);
        MN.x = fminf(MN.x, i.x); MN.y = fminf(MN.y, i.y);
        MN.z = fminf(MN.z, i.z); MN.w = fminf(MN.w, i.w);
    }
    const float4 bb = *reinterpret_cast<const float4*>(bias + (i4 & (N_OUT - 1)));
    float4 o;
    o.x = MX.x + MN.x + bb.x; o.y = MX.y + MN.y + bb.y;
    o.z = MX.z + MN.z + bb.z; o.w = MX.w + MN.w + bb.w;
    *reinterpret_cast<float4*>(out + i4) = o;
}

// ---------------- Fallback (workspace too small) ----------------
__global__ __launch_bounds__(256)
void mam_simple(const float* __restrict__ x, const float* __restrict__ w,
                const float* __restrict__ bias, float* __restrict__ out) {
    const int idx = blockIdx.x * 256 + threadIdx.x;
    const int b = idx / N_OUT, n = idx % N_OUT;
    const float* xr = x + (size_t)b * K_IN;
    const float* wr = w + (size_t)n * K_IN;
    float mx = -FLT_MAX, mn = FLT_MAX;
#pragma unroll 4
    for (int k = 0; k < K_IN; k += 4) {
        const float4 xv = *reinterpret_cast<const float4*>(xr + k);
        const float4 wv = *reinterpret_cast<const float4*>(wr + k);
        const float p0 = xv.x * wv.x, p1 = xv.y * wv.y;
        const float p2 = xv.z * wv.z, p3 = xv.w * wv.w;
        mx = fmaxf(fmaxf(mx, p0), p1);
        mx = fmaxf(fmaxf(mx, p2), p3);
        mn = fminf(fminf(mn, p0), p1);
        mn = fminf(fminf(mn, p2), p3);
    }
    out[idx] = mx + mn + bias[n];
}

extern "C" void kernel_launch(void* const* d_in, const int* in_sizes, int n_in,
                              void* d_out, int out_size, void* d_ws, size_t ws_size,
                              hipStream_t stream) {
    const float* x    = (const float*)d_in[0];   // [256,1024]
    const float* w    = (const float*)d_in[1];   // [512,1024]
    const float* bias = (const float*)d_in[2];   // [512]
    float* out = (float*)d_out;                  // [256,512] f32

    const size_t plane = (size_t)B_TOK * N_OUT;
    const size_t wT_sz = (size_t)K_IN * N_OUT;                       // 2MB
    const size_t need  = (wT_sz + 2 * (size_t)KC_NUM * plane) * sizeof(float);  // 18MB

    if (ws_size >= need) {
        float* wT  = (float*)d_ws;
        float* pmx = wT + wT_sz;
        float* pmn = pmx + (size_t)KC_NUM * plane;
        w_transpose<<<dim3(K_IN / 64, N_OUT / 64), 256, 0, stream>>>(w, wT);
        mam_stage1<<<dim3(B_TOK / 8, KC_NUM), 256, 0, stream>>>(x, wT, pmx, pmn);
        mam_stage2<<<(int)(plane / 4 / 256), 256, 0, stream>>>(pmx, pmn, bias, out);
    } else {
        mam_simple<<<(B_TOK * N_OUT) / 256, 256, 0, stream>>>(x, w, bias, out);
    }
}